// Round 2
// baseline (483.059 us; speedup 1.0000x reference)
//
#include <hip/hip_runtime.h>

// 12-bit ripple-borrow subtractor on binary spike inputs (floats 0.0/1.0).
//
// R4: R3 + non-temporal stores.
//   Evidence: R2 (LDS transpose, 55% occ) and R3 (streaming, 80% occ) both
//   run 153 us at exactly 2.75 TB/s HBM -> memory-system wall, not structure.
//   FETCH_SIZE (~199 MB) is only half the 402 MB input: the other half hits
//   the 256 MB Infinity Cache across dispatches. The 218 MB of output writes
//   write-allocate in LLC each dispatch and evict input. D/Borrow are never
//   read -> stream them past the cache with the `nt` flag
//   (__builtin_nontemporal_store) so more of A/B stays LLC-resident.
//   Predicted: FETCH_SIZE 199 -> ~150-170 MB; if HBM-rate-bound, dur
//   153 -> ~135-142 us. If dur is unchanged, the wall is demand-side fabric
//   and we are at the structural ceiling.
//
//   Bit logic in integer domain: on {0.0f, 1.0f} inputs, bit 23 (exponent
//   LSB) of the IEEE-754 encoding is exactly the boolean value.

typedef unsigned int v4u __attribute__((ext_vector_type(4)));

__global__ __launch_bounds__(256, 8) void Subtractor12Bit_kernel(
    const v4u* __restrict__ A4,      // [batch*3] (raw f32 bits)
    const v4u* __restrict__ B4,
    v4u* __restrict__ D4,            // diffs, [batch*3]
    float* __restrict__ Borrow,      // [batch]
    int batch)
{
    const int row = blockIdx.x * 256 + threadIdx.x;
    if (row >= batch) return;
    const int base = row * 3;        // max 12.58M, fits int32

    const v4u a0 = A4[base + 0];
    const v4u a1 = A4[base + 1];
    const v4u a2 = A4[base + 2];
    const v4u b0 = B4[base + 0];
    const v4u b1 = B4[base + 1];
    const v4u b2 = B4[base + 2];

    // Pack 12 bits. Input index 0 = MSB (bit 11), index 11 = LSB (bit 0).
    const unsigned ua =
        (((a0[0] >> 23) & 1u) << 11) | (((a0[1] >> 23) & 1u) << 10) |
        (((a0[2] >> 23) & 1u) <<  9) | (((a0[3] >> 23) & 1u) <<  8) |
        (((a1[0] >> 23) & 1u) <<  7) | (((a1[1] >> 23) & 1u) <<  6) |
        (((a1[2] >> 23) & 1u) <<  5) | (((a1[3] >> 23) & 1u) <<  4) |
        (((a2[0] >> 23) & 1u) <<  3) | (((a2[1] >> 23) & 1u) <<  2) |
        (((a2[2] >> 23) & 1u) <<  1) | (((a2[3] >> 23) & 1u)      );
    const unsigned ub =
        (((b0[0] >> 23) & 1u) << 11) | (((b0[1] >> 23) & 1u) << 10) |
        (((b0[2] >> 23) & 1u) <<  9) | (((b0[3] >> 23) & 1u) <<  8) |
        (((b1[0] >> 23) & 1u) <<  7) | (((b1[1] >> 23) & 1u) <<  6) |
        (((b1[2] >> 23) & 1u) <<  5) | (((b1[3] >> 23) & 1u) <<  4) |
        (((b2[0] >> 23) & 1u) <<  3) | (((b2[1] >> 23) & 1u) <<  2) |
        (((b2[2] >> 23) & 1u) <<  1) | (((b2[3] >> 23) & 1u)      );

    const unsigned diff = (ua - ub) & 0xFFFu;

    // Borrow out: 1.0f iff b > a. Coalesced 4B/lane, streamed past LLC.
    __builtin_nontemporal_store((ub > ua) ? 1.0f : 0.0f, &Borrow[row]);

    // Unpack: bit -> 0x3F800000 (1.0f) or 0, via mask = 0 - bit.
    const unsigned ONE = 0x3F800000u;
    v4u d0, d1, d2;
    d0[0] = ONE & (0u - ((diff >> 11) & 1u));
    d0[1] = ONE & (0u - ((diff >> 10) & 1u));
    d0[2] = ONE & (0u - ((diff >>  9) & 1u));
    d0[3] = ONE & (0u - ((diff >>  8) & 1u));
    d1[0] = ONE & (0u - ((diff >>  7) & 1u));
    d1[1] = ONE & (0u - ((diff >>  6) & 1u));
    d1[2] = ONE & (0u - ((diff >>  5) & 1u));
    d1[3] = ONE & (0u - ((diff >>  4) & 1u));
    d2[0] = ONE & (0u - ((diff >>  3) & 1u));
    d2[1] = ONE & (0u - ((diff >>  2) & 1u));
    d2[2] = ONE & (0u - ((diff >>  1) & 1u));
    d2[3] = ONE & (0u - ( diff        & 1u));

    __builtin_nontemporal_store(d0, &D4[base + 0]);
    __builtin_nontemporal_store(d1, &D4[base + 1]);
    __builtin_nontemporal_store(d2, &D4[base + 2]);
}

extern "C" void kernel_launch(void* const* d_in, const int* in_sizes, int n_in,
                              void* d_out, int out_size, void* d_ws, size_t ws_size,
                              hipStream_t stream) {
    const float* A = (const float*)d_in[0];
    const float* B = (const float*)d_in[1];
    float* out = (float*)d_out;

    const int batch = in_sizes[0] / 12;             // 4,194,304
    float* diffs = out;                             // [batch*12]
    float* borrow = out + (size_t)batch * 12;       // [batch]

    const int grid = (batch + 255) / 256;           // 16384
    Subtractor12Bit_kernel<<<grid, 256, 0, stream>>>(
        (const v4u*)A, (const v4u*)B, (v4u*)diffs, borrow, batch);
}

// Round 3
// 468.245 us; speedup vs baseline: 1.0316x; 1.0316x over previous
//
#include <hip/hip_runtime.h>

// 12-bit ripple-borrow subtractor on binary spike inputs (floats 0.0/1.0).
//
// R5: persistent grid-stride + register double-buffer. nt stores REVERTED
//   (R4: nt amplified WRITE_SIZE 213->265 MB via unmerged partial-line
//   streams; dur 153->185 us. Cached stores merge 48B-stride rows in L2).
//
//   Evidence so far: R2 (LDS transpose) == R3 (streaming one-shot) == 153 us
//   at 4.05 TB/s demand / 2.7 TB/s HBM-side; no pipe saturated (VALU 7.6%,
//   occ 80%). Wave residency ~15 us for ~30 instructions => deep memory
//   queuing under maximally bursty one-shot workgroup churn (16384 WGs,
//   each issues its whole 12KB of line requests at birth, stalls, dies).
//   R5 replaces churn with 2048 persistent blocks (32 waves/CU); each
//   thread walks 8 rows at grid stride, issuing next-row loads BEFORE
//   computing the current row -> every wave holds a steady 6 loads in
//   flight for its whole life (copy-ubench-style smooth request stream).
//
//   Bit logic in integer domain: on {0.0f,1.0f} inputs, bit 23 of the
//   IEEE-754 encoding is exactly the boolean value.

typedef unsigned int v4u __attribute__((ext_vector_type(4)));

#define NBLOCKS 2048   // 8 blocks/CU, 32 waves/CU if VGPR<=64

__device__ __forceinline__ unsigned pack12(v4u x0, v4u x1, v4u x2) {
    // Input index 0 = MSB (bit 11), index 11 = LSB (bit 0).
    return (((x0[0] >> 23) & 1u) << 11) | (((x0[1] >> 23) & 1u) << 10) |
           (((x0[2] >> 23) & 1u) <<  9) | (((x0[3] >> 23) & 1u) <<  8) |
           (((x1[0] >> 23) & 1u) <<  7) | (((x1[1] >> 23) & 1u) <<  6) |
           (((x1[2] >> 23) & 1u) <<  5) | (((x1[3] >> 23) & 1u) <<  4) |
           (((x2[0] >> 23) & 1u) <<  3) | (((x2[1] >> 23) & 1u) <<  2) |
           (((x2[2] >> 23) & 1u) <<  1) | (((x2[3] >> 23) & 1u)      );
}

__global__ __launch_bounds__(256, 8) void Subtractor12Bit_kernel(
    const v4u* __restrict__ A4,      // [batch*3] (raw f32 bits)
    const v4u* __restrict__ B4,
    v4u* __restrict__ D4,            // diffs, [batch*3]
    float* __restrict__ Borrow,      // [batch]
    int batch)
{
    const int stride = NBLOCKS * 256;            // 524288 rows per sweep
    int r = blockIdx.x * 256 + threadIdx.x;
    if (r >= batch) return;

    // Prologue: load row r.
    v4u a0 = A4[r * 3 + 0], a1 = A4[r * 3 + 1], a2 = A4[r * 3 + 2];
    v4u b0 = B4[r * 3 + 0], b1 = B4[r * 3 + 1], b2 = B4[r * 3 + 2];

    while (true) {
        // Issue next row's loads first: 6 loads stay in flight while we
        // compute/store the current row (compiler emits vmcnt(6) waits).
        const int rn = r + stride;
        const bool has = rn < batch;
        v4u na0, na1, na2, nb0, nb1, nb2;
        if (has) {
            na0 = A4[rn * 3 + 0]; na1 = A4[rn * 3 + 1]; na2 = A4[rn * 3 + 2];
            nb0 = B4[rn * 3 + 0]; nb1 = B4[rn * 3 + 1]; nb2 = B4[rn * 3 + 2];
        }

        // ---- compute + store row r ----
        const unsigned ua = pack12(a0, a1, a2);
        const unsigned ub = pack12(b0, b1, b2);
        const unsigned diff = (ua - ub) & 0xFFFu;

        Borrow[r] = (ub > ua) ? 1.0f : 0.0f;     // coalesced 4B/lane

        const unsigned ONE = 0x3F800000u;        // bit -> 1.0f via mask
        v4u d0, d1, d2;
        d0[0] = ONE & (0u - ((diff >> 11) & 1u));
        d0[1] = ONE & (0u - ((diff >> 10) & 1u));
        d0[2] = ONE & (0u - ((diff >>  9) & 1u));
        d0[3] = ONE & (0u - ((diff >>  8) & 1u));
        d1[0] = ONE & (0u - ((diff >>  7) & 1u));
        d1[1] = ONE & (0u - ((diff >>  6) & 1u));
        d1[2] = ONE & (0u - ((diff >>  5) & 1u));
        d1[3] = ONE & (0u - ((diff >>  4) & 1u));
        d2[0] = ONE & (0u - ((diff >>  3) & 1u));
        d2[1] = ONE & (0u - ((diff >>  2) & 1u));
        d2[2] = ONE & (0u - ((diff >>  1) & 1u));
        d2[3] = ONE & (0u - ( diff        & 1u));

        D4[r * 3 + 0] = d0;
        D4[r * 3 + 1] = d1;
        D4[r * 3 + 2] = d2;

        if (!has) break;
        r = rn;
        a0 = na0; a1 = na1; a2 = na2;
        b0 = nb0; b1 = nb1; b2 = nb2;
    }
}

extern "C" void kernel_launch(void* const* d_in, const int* in_sizes, int n_in,
                              void* d_out, int out_size, void* d_ws, size_t ws_size,
                              hipStream_t stream) {
    const float* A = (const float*)d_in[0];
    const float* B = (const float*)d_in[1];
    float* out = (float*)d_out;

    const int batch = in_sizes[0] / 12;             // 4,194,304
    float* diffs = out;                             // [batch*12]
    float* borrow = out + (size_t)batch * 12;       // [batch]

    const int maxGrid = (batch + 255) / 256;
    const int grid = (NBLOCKS < maxGrid) ? NBLOCKS : maxGrid;
    Subtractor12Bit_kernel<<<grid, 256, 0, stream>>>(
        (const v4u*)A, (const v4u*)B, (v4u*)diffs, borrow, batch);
}